// Round 1
// baseline (613.108 us; speedup 1.0000x reference)
//
#include <hip/hip_runtime.h>
#include <hip/hip_bf16.h>

typedef short bf16x8 __attribute__((ext_vector_type(8)));
typedef float f32x4 __attribute__((ext_vector_type(4)));

#define EMB 1024
#define NH 16
#define SEQ 2048
#define BATCH 4
#define MROWS (BATCH * SEQ)

static __device__ inline unsigned short f2bf(float f) {
  unsigned u = __float_as_uint(f);
  u += 0x7fffu + ((u >> 16) & 1u);
  return (unsigned short)(u >> 16);
}

// ---------------- weight transpose + cast: W[k][n] f32 -> WT[n][k] bf16 ----------------
__global__ __launch_bounds__(256) void wtrans_kernel(
    const float* w0, const float* w1, const float* w2, const float* w3,
    unsigned short* o0, unsigned short* o1, unsigned short* o2, unsigned short* o3) {
  __shared__ float t[32][33];
  int z = blockIdx.z;
  const float* W = z == 0 ? w0 : z == 1 ? w1 : z == 2 ? w2 : w3;
  unsigned short* O = z == 0 ? o0 : z == 1 ? o1 : z == 2 ? o2 : o3;
  int bx = blockIdx.x * 32;  // k block
  int by = blockIdx.y * 32;  // n block
  int tx = threadIdx.x, ty = threadIdx.y;  // (32,8)
#pragma unroll
  for (int j = 0; j < 4; ++j)
    t[ty + j * 8][tx] = W[(size_t)(bx + ty + j * 8) * EMB + by + tx];
  __syncthreads();
#pragma unroll
  for (int j = 0; j < 4; ++j)
    O[(size_t)(by + ty + j * 8) * EMB + bx + tx] = f2bf(t[tx][ty + j * 8]);
}

// ---------------- GEMM: C[M=8192][N=1024] = A[M][K=1024] * BT[N][K]^T ----------------
// IN_F32: 1 = A is f32 (cast to bf16 while staging), 0 = A is bf16
// OUT_MODE: 0 = bf16 normal [m][n], 1 = bf16 V-transposed [b][h][dv][l], 2 = f32 [m][n]
template <int IN_F32, int OUT_MODE>
__global__ __launch_bounds__(256) void gemm_kernel(const void* Ap, const unsigned short* Bt, void* Cp) {
  __shared__ __align__(16) unsigned short As[128][72];
  __shared__ __align__(16) unsigned short Bs[128][72];
  const int K = EMB;
  int tid = threadIdx.x;
  int lane = tid & 63, wave = tid >> 6;
  int q = lane & 15, g = lane >> 4;
  int wm = (wave >> 1) * 64, wn = (wave & 1) * 64;
  int tm = blockIdx.y * 128, tn = blockIdx.x * 128;
  f32x4 acc[4][4] = {};
  for (int kt = 0; kt < K; kt += 64) {
    if (IN_F32) {
      const float* A = (const float*)Ap;
#pragma unroll
      for (int it = 0; it < 4; ++it) {
        int gid = tid + it * 256;
        int row = gid >> 3, kg = (gid & 7) * 8;
        const float4* s0 = (const float4*)(A + (size_t)(tm + row) * K + kt + kg);
        float4 x = s0[0], y = s0[1];
        bf16x8 v;
        v[0] = f2bf(x.x); v[1] = f2bf(x.y); v[2] = f2bf(x.z); v[3] = f2bf(x.w);
        v[4] = f2bf(y.x); v[5] = f2bf(y.y); v[6] = f2bf(y.z); v[7] = f2bf(y.w);
        *(bf16x8*)&As[row][kg] = v;
      }
    } else {
      const unsigned short* A = (const unsigned short*)Ap;
#pragma unroll
      for (int it = 0; it < 4; ++it) {
        int gid = tid + it * 256;
        int row = gid >> 3, kg = (gid & 7) * 8;
        *(bf16x8*)&As[row][kg] = *(const bf16x8*)(A + (size_t)(tm + row) * K + kt + kg);
      }
    }
#pragma unroll
    for (int it = 0; it < 4; ++it) {
      int gid = tid + it * 256;
      int row = gid >> 3, kg = (gid & 7) * 8;
      *(bf16x8*)&Bs[row][kg] = *(const bf16x8*)(Bt + (size_t)(tn + row) * K + kt + kg);
    }
    __syncthreads();
#pragma unroll
    for (int ks = 0; ks < 64; ks += 32) {
      bf16x8 af[4], bfr[4];
#pragma unroll
      for (int mf = 0; mf < 4; ++mf)
        af[mf] = *(const bf16x8*)&As[wm + mf * 16 + q][ks + 8 * g];
#pragma unroll
      for (int nf = 0; nf < 4; ++nf)
        bfr[nf] = *(const bf16x8*)&Bs[wn + nf * 16 + q][ks + 8 * g];
#pragma unroll
      for (int mf = 0; mf < 4; ++mf)
#pragma unroll
        for (int nf = 0; nf < 4; ++nf)
          acc[mf][nf] = __builtin_amdgcn_mfma_f32_16x16x32_bf16(af[mf], bfr[nf], acc[mf][nf], 0, 0, 0);
    }
    __syncthreads();
  }
  if (OUT_MODE == 0) {
    unsigned short* C = (unsigned short*)Cp;
#pragma unroll
    for (int mf = 0; mf < 4; ++mf)
#pragma unroll
      for (int nf = 0; nf < 4; ++nf)
#pragma unroll
        for (int r = 0; r < 4; ++r) {
          int row = tm + wm + mf * 16 + 4 * g + r;
          int col = tn + wn + nf * 16 + q;
          C[(size_t)row * EMB + col] = f2bf(acc[mf][nf][r]);
        }
  } else if (OUT_MODE == 1) {
    unsigned short* C = (unsigned short*)Cp;
#pragma unroll
    for (int mf = 0; mf < 4; ++mf) {
      int m0 = tm + wm + mf * 16 + 4 * g;
      int b = m0 >> 11, l = m0 & 2047;
#pragma unroll
      for (int nf = 0; nf < 4; ++nf) {
        int n = tn + wn + nf * 16 + q;
        int h = n >> 6, dv = n & 63;
        short4 v;
        v.x = (short)f2bf(acc[mf][nf][0]);
        v.y = (short)f2bf(acc[mf][nf][1]);
        v.z = (short)f2bf(acc[mf][nf][2]);
        v.w = (short)f2bf(acc[mf][nf][3]);
        *(short4*)&C[(((size_t)b * NH + h) * 64 + dv) * SEQ + l] = v;
      }
    }
  } else {
    float* C = (float*)Cp;
#pragma unroll
    for (int mf = 0; mf < 4; ++mf)
#pragma unroll
      for (int nf = 0; nf < 4; ++nf)
#pragma unroll
        for (int r = 0; r < 4; ++r) {
          int row = tm + wm + mf * 16 + 4 * g + r;
          int col = tn + wn + nf * 16 + q;
          C[(size_t)row * EMB + col] = acc[mf][nf][r];
        }
  }
}

// ---------------- flash attention, swapped operands ----------------
// Q,K bf16 [b][l][h*64+d]; VT bf16 [b][h][dv][l]; out bf16 [b][l][h*64+dv]
__global__ __launch_bounds__(256) void attn_kernel(
    const unsigned short* Qb, const unsigned short* Kb, const unsigned short* VTb,
    const int* pad, unsigned short* Ob) {
  __shared__ __align__(16) unsigned short P_lds[4][16][72];
  int tid = threadIdx.x;
  int lane = tid & 63, wave = tid >> 6;
  int q = lane & 15, g = lane >> 4;
  int h = blockIdx.y, b = blockIdx.z;
  int qs = blockIdx.x * 64 + wave * 16;
  int qg = qs + q;  // this lane's global query row (within sequence)
  const unsigned short* Qrow = Qb + ((size_t)(b * SEQ + qg)) * EMB + h * 64;
  bf16x8 qf0 = *(const bf16x8*)(Qrow + 8 * g);
  bf16x8 qf1 = *(const bf16x8*)(Qrow + 32 + 8 * g);
  f32x4 o[4] = {};
  float m_run = -INFINITY, l_run = 0.f;
  int ntiles = blockIdx.x + 1;
  for (int t = 0; t < ntiles; ++t) {
    int kvt = t * 64;
    int pv = pad[b * SEQ + kvt + lane];
    unsigned long long pmask = __ballot(pv != 0);
    // S^T[kv 64][q 16] = K * Q^T
    f32x4 sf[4] = {};
#pragma unroll
    for (int s = 0; s < 2; ++s) {
#pragma unroll
      for (int mf = 0; mf < 4; ++mf) {
        bf16x8 kf = *(const bf16x8*)(Kb + ((size_t)(b * SEQ + kvt + mf * 16 + q)) * EMB + h * 64 + s * 32 + 8 * g);
        sf[mf] = __builtin_amdgcn_mfma_f32_16x16x32_bf16(kf, s == 0 ? qf0 : qf1, sf[mf], 0, 0, 0);
      }
    }
    // scale + causal + pad mask; tile max
    float tmax = -INFINITY;
#pragma unroll
    for (int mf = 0; mf < 4; ++mf)
#pragma unroll
      for (int r = 0; r < 4; ++r) {
        int kvl = mf * 16 + 4 * g + r;
        int kvg = kvt + kvl;
        float sv = sf[mf][r] * 0.125f;
        bool keep = (kvg <= qg) && ((pmask >> kvl) & 1ULL);
        sv = keep ? sv : -INFINITY;
        sf[mf][r] = sv;
        tmax = fmaxf(tmax, sv);
      }
    tmax = fmaxf(tmax, __shfl_xor(tmax, 16));
    tmax = fmaxf(tmax, __shfl_xor(tmax, 32));
    float m_new = fmaxf(m_run, tmax);
    float alpha = __expf(m_run - m_new);
    float rsum = 0.f;
#pragma unroll
    for (int mf = 0; mf < 4; ++mf) {
      short4 pk;
#pragma unroll
      for (int r = 0; r < 4; ++r) {
        float p = __expf(sf[mf][r] - m_new);
        rsum += p;
        ((short*)&pk)[r] = (short)f2bf(p);
      }
      *(short4*)&P_lds[wave][q][mf * 16 + 4 * g] = pk;
    }
    rsum += __shfl_xor(rsum, 16);
    rsum += __shfl_xor(rsum, 32);
    l_run = l_run * alpha + rsum;
    m_run = m_new;
#pragma unroll
    for (int mv = 0; mv < 4; ++mv) o[mv] *= alpha;
    // O^T[dv][q] += V^T[dv][kv] * P^T[kv][q]
#pragma unroll
    for (int s = 0; s < 2; ++s) {
      bf16x8 pb = *(const bf16x8*)&P_lds[wave][q][s * 32 + 8 * g];
#pragma unroll
      for (int mv = 0; mv < 4; ++mv) {
        bf16x8 va = *(const bf16x8*)(VTb + (((size_t)(b * NH + h)) * 64 + mv * 16 + q) * SEQ + kvt + s * 32 + 8 * g);
        o[mv] = __builtin_amdgcn_mfma_f32_16x16x32_bf16(va, pb, o[mv], 0, 0, 0);
      }
    }
  }
  float inv = 1.0f / l_run;
  unsigned short* Orow = Ob + ((size_t)(b * SEQ + qg)) * EMB + h * 64;
#pragma unroll
  for (int mv = 0; mv < 4; ++mv) {
    short4 v;
    v.x = (short)f2bf(o[mv][0] * inv);
    v.y = (short)f2bf(o[mv][1] * inv);
    v.z = (short)f2bf(o[mv][2] * inv);
    v.w = (short)f2bf(o[mv][3] * inv);
    *(short4*)&Orow[mv * 16 + 4 * g] = v;
  }
}

extern "C" void kernel_launch(void* const* d_in, const int* in_sizes, int n_in,
                              void* d_out, int out_size, void* d_ws, size_t ws_size,
                              hipStream_t stream) {
  const float* query = (const float*)d_in[0];
  const float* key   = (const float*)d_in[1];
  const float* value = (const float*)d_in[2];
  const int*   pad   = (const int*)d_in[3];
  const float* Wq = (const float*)d_in[4];
  const float* Wk = (const float*)d_in[5];
  const float* Wv = (const float*)d_in[6];
  const float* Wo = (const float*)d_in[7];

  unsigned short* WqT = (unsigned short*)d_ws;
  unsigned short* WkT = WqT + (size_t)EMB * EMB;
  unsigned short* WvT = WkT + (size_t)EMB * EMB;
  unsigned short* WoT = WvT + (size_t)EMB * EMB;
  unsigned short* Qb  = WoT + (size_t)EMB * EMB;
  unsigned short* Kb  = Qb + (size_t)MROWS * EMB;
  unsigned short* VTb = Kb + (size_t)MROWS * EMB;
  unsigned short* Ab  = VTb + (size_t)MROWS * EMB;

  wtrans_kernel<<<dim3(EMB / 32, EMB / 32, 4), dim3(32, 8), 0, stream>>>(
      Wq, Wk, Wv, Wo, WqT, WkT, WvT, WoT);
  gemm_kernel<1, 0><<<dim3(8, 64), 256, 0, stream>>>(query, WqT, Qb);
  gemm_kernel<1, 0><<<dim3(8, 64), 256, 0, stream>>>(key, WkT, Kb);
  gemm_kernel<1, 1><<<dim3(8, 64), 256, 0, stream>>>(value, WvT, VTb);
  attn_kernel<<<dim3(SEQ / 64, NH, BATCH), 256, 0, stream>>>(Qb, Kb, VTb, pad, Ab);
  gemm_kernel<0, 2><<<dim3(8, 64), 256, 0, stream>>>(Ab, WoT, d_out);
}

// Round 2
// 264.116 us; speedup vs baseline: 2.3214x; 2.3214x over previous
//
#include <hip/hip_runtime.h>
#include <hip/hip_bf16.h>

typedef short bf16x8 __attribute__((ext_vector_type(8)));
typedef float f32x4 __attribute__((ext_vector_type(4)));

#define EMB 1024
#define NH 16
#define SEQ 2048
#define BATCH 4
#define MROWS (BATCH * SEQ)

static __device__ inline unsigned short f2bf(float f) {
  unsigned u = __float_as_uint(f);
  u += 0x7fffu + ((u >> 16) & 1u);
  return (unsigned short)(u >> 16);
}

// ---------------- weight transpose + cast: W[k][n] f32 -> WT[n][k] bf16 ----------------
__global__ __launch_bounds__(256) void wtrans_kernel(
    const float* w0, const float* w1, const float* w2, const float* w3,
    unsigned short* o0, unsigned short* o1, unsigned short* o2, unsigned short* o3) {
  __shared__ float t[32][33];
  int z = blockIdx.z;
  const float* W = z == 0 ? w0 : z == 1 ? w1 : z == 2 ? w2 : w3;
  unsigned short* O = z == 0 ? o0 : z == 1 ? o1 : z == 2 ? o2 : o3;
  int bx = blockIdx.x * 32;  // k block
  int by = blockIdx.y * 32;  // n block
  int tx = threadIdx.x, ty = threadIdx.y;  // (32,8)
#pragma unroll
  for (int j = 0; j < 4; ++j)
    t[ty + j * 8][tx] = W[(size_t)(bx + ty + j * 8) * EMB + by + tx];
  __syncthreads();
#pragma unroll
  for (int j = 0; j < 4; ++j)
    O[(size_t)(by + ty + j * 8) * EMB + bx + tx] = f2bf(t[tx][ty + j * 8]);
}

// ---------------- GEMM: C[M=8192][N=1024] = A[M][K=1024] * BT[N][K]^T ----------------
// IN_F32: 1 = A is f32 (cast to bf16 while staging), 0 = A is bf16
// OUT_MODE: 0 = bf16 normal [m][n], 1 = bf16 V-transposed [b][h][dv][l], 2 = f32 [m][n]
template <int IN_F32, int OUT_MODE>
__global__ __launch_bounds__(256) void gemm_kernel(const void* Ap, const unsigned short* Bt, void* Cp) {
  __shared__ __align__(16) unsigned short As[128][72];
  __shared__ __align__(16) unsigned short Bs[128][72];
  const int K = EMB;
  int tid = threadIdx.x;
  int lane = tid & 63, wave = tid >> 6;
  int q = lane & 15, g = lane >> 4;
  int wm = (wave >> 1) * 64, wn = (wave & 1) * 64;
  int tm = blockIdx.y * 128, tn = blockIdx.x * 128;
  f32x4 acc[4][4] = {};
  for (int kt = 0; kt < K; kt += 64) {
    if (IN_F32) {
      const float* A = (const float*)Ap;
#pragma unroll
      for (int it = 0; it < 4; ++it) {
        int gid = tid + it * 256;
        int row = gid >> 3, kg = (gid & 7) * 8;
        const float4* s0 = (const float4*)(A + (size_t)(tm + row) * K + kt + kg);
        float4 x = s0[0], y = s0[1];
        bf16x8 v;
        v[0] = f2bf(x.x); v[1] = f2bf(x.y); v[2] = f2bf(x.z); v[3] = f2bf(x.w);
        v[4] = f2bf(y.x); v[5] = f2bf(y.y); v[6] = f2bf(y.z); v[7] = f2bf(y.w);
        *(bf16x8*)&As[row][kg] = v;
      }
    } else {
      const unsigned short* A = (const unsigned short*)Ap;
#pragma unroll
      for (int it = 0; it < 4; ++it) {
        int gid = tid + it * 256;
        int row = gid >> 3, kg = (gid & 7) * 8;
        *(bf16x8*)&As[row][kg] = *(const bf16x8*)(A + (size_t)(tm + row) * K + kt + kg);
      }
    }
#pragma unroll
    for (int it = 0; it < 4; ++it) {
      int gid = tid + it * 256;
      int row = gid >> 3, kg = (gid & 7) * 8;
      *(bf16x8*)&Bs[row][kg] = *(const bf16x8*)(Bt + (size_t)(tn + row) * K + kt + kg);
    }
    __syncthreads();
#pragma unroll
    for (int ks = 0; ks < 64; ks += 32) {
      bf16x8 af[4], bfr[4];
#pragma unroll
      for (int mf = 0; mf < 4; ++mf)
        af[mf] = *(const bf16x8*)&As[wm + mf * 16 + q][ks + 8 * g];
#pragma unroll
      for (int nf = 0; nf < 4; ++nf)
        bfr[nf] = *(const bf16x8*)&Bs[wn + nf * 16 + q][ks + 8 * g];
#pragma unroll
      for (int mf = 0; mf < 4; ++mf)
#pragma unroll
        for (int nf = 0; nf < 4; ++nf)
          acc[mf][nf] = __builtin_amdgcn_mfma_f32_16x16x32_bf16(af[mf], bfr[nf], acc[mf][nf], 0, 0, 0);
    }
    __syncthreads();
  }
  if (OUT_MODE == 0) {
    unsigned short* C = (unsigned short*)Cp;
#pragma unroll
    for (int mf = 0; mf < 4; ++mf)
#pragma unroll
      for (int nf = 0; nf < 4; ++nf)
#pragma unroll
        for (int r = 0; r < 4; ++r) {
          int row = tm + wm + mf * 16 + 4 * g + r;
          int col = tn + wn + nf * 16 + q;
          C[(size_t)row * EMB + col] = f2bf(acc[mf][nf][r]);
        }
  } else if (OUT_MODE == 1) {
    unsigned short* C = (unsigned short*)Cp;
#pragma unroll
    for (int mf = 0; mf < 4; ++mf) {
      int m0 = tm + wm + mf * 16 + 4 * g;
      int b = m0 >> 11, l = m0 & 2047;
#pragma unroll
      for (int nf = 0; nf < 4; ++nf) {
        int n = tn + wn + nf * 16 + q;
        int h = n >> 6, dv = n & 63;
        short4 v;
        v.x = (short)f2bf(acc[mf][nf][0]);
        v.y = (short)f2bf(acc[mf][nf][1]);
        v.z = (short)f2bf(acc[mf][nf][2]);
        v.w = (short)f2bf(acc[mf][nf][3]);
        *(short4*)&C[(((size_t)b * NH + h) * 64 + dv) * SEQ + l] = v;
      }
    }
  } else {
    float* C = (float*)Cp;
#pragma unroll
    for (int mf = 0; mf < 4; ++mf)
#pragma unroll
      for (int nf = 0; nf < 4; ++nf)
#pragma unroll
        for (int r = 0; r < 4; ++r) {
          int row = tm + wm + mf * 16 + 4 * g + r;
          int col = tn + wn + nf * 16 + q;
          C[(size_t)row * EMB + col] = acc[mf][nf][r];
        }
  }
}

// ---------------- flash attention, LDS-staged K/V, swapped operands ----------------
// Q,K bf16 [b][l][h*64+d]; VT bf16 [b][h][dv][l]; out bf16 [b][l][h*64+dv]
// Block = 4 waves = 64 q rows per chunk; block x handles chunks {x, 31-x} (balanced).
__global__ __launch_bounds__(256) void attn_kernel(
    const unsigned short* Qb, const unsigned short* Kb, const unsigned short* VTb,
    const int* pad, unsigned short* Ob) {
  __shared__ __align__(16) unsigned short Ks[64 * 64];      // XOR-swizzled [kv][d]
  __shared__ __align__(16) unsigned short Vs[64 * 64];      // XOR-swizzled [dv][kv]
  __shared__ __align__(16) unsigned short Ps[4][16 * 64];   // per-wave P, XOR-swizzled [q][kv]
  const float SC = 0.18033688011112042f;  // 0.125 * log2(e)
  int tid = threadIdx.x;
  int lane = tid & 63, wave = tid >> 6;
  int q = lane & 15, g = lane >> 4;
  int h = blockIdx.y, b = blockIdx.z;
  int qx7 = q & 7;

#pragma unroll 1
  for (int half = 0; half < 2; ++half) {
    int c = half ? 31 - (int)blockIdx.x : (int)blockIdx.x;
    int qg = c * 64 + wave * 16 + q;
    const unsigned short* Qrow = Qb + ((size_t)(b * SEQ + qg)) * EMB + h * 64;
    bf16x8 qf0 = *(const bf16x8*)(Qrow + 8 * g);
    bf16x8 qf1 = *(const bf16x8*)(Qrow + 32 + 8 * g);
    f32x4 o[4] = {};
    float m_run = -INFINITY, l_run = 0.f;
#pragma unroll 1
    for (int t = 0; t <= c; ++t) {
      int kvt = t * 64;
      __syncthreads();  // previous tile's LDS reads complete before overwrite
#pragma unroll
      for (int it = 0; it < 2; ++it) {
        int gid = tid + it * 256;
        int row = gid >> 3, cb = gid & 7;
        int dst = row * 64 + 8 * (cb ^ (row & 7));
        *(bf16x8*)&Ks[dst] = *(const bf16x8*)(Kb + ((size_t)(b * SEQ + kvt + row)) * EMB + h * 64 + cb * 8);
        *(bf16x8*)&Vs[dst] = *(const bf16x8*)(VTb + (((size_t)(b * NH + h)) * 64 + row) * SEQ + kvt + cb * 8);
      }
      int pv = pad[b * SEQ + kvt + lane];
      unsigned long long pmask = __ballot(pv != 0);
      __syncthreads();
      // S^T[kv 64][q 16] = K * Q^T
      f32x4 sf[4] = {};
#pragma unroll
      for (int s = 0; s < 2; ++s) {
#pragma unroll
        for (int mf = 0; mf < 4; ++mf) {
          bf16x8 kf = *(const bf16x8*)&Ks[(mf * 16 + q) * 64 + 8 * ((4 * s + g) ^ qx7)];
          sf[mf] = __builtin_amdgcn_mfma_f32_16x16x32_bf16(kf, s ? qf1 : qf0, sf[mf], 0, 0, 0);
        }
      }
      // scale (log2 domain) + causal + pad mask; tile max
      float tmax = -INFINITY;
      bool full = (t < c) && (pmask == ~0ull);
      if (full) {
#pragma unroll
        for (int mf = 0; mf < 4; ++mf)
#pragma unroll
          for (int r = 0; r < 4; ++r) {
            float sv = sf[mf][r] * SC;
            sf[mf][r] = sv;
            tmax = fmaxf(tmax, sv);
          }
      } else {
#pragma unroll
        for (int mf = 0; mf < 4; ++mf)
#pragma unroll
          for (int r = 0; r < 4; ++r) {
            int kvl = mf * 16 + 4 * g + r;
            float sv = sf[mf][r] * SC;
            bool keep = (kvt + kvl <= qg) && ((pmask >> kvl) & 1ULL);
            sv = keep ? sv : -INFINITY;
            sf[mf][r] = sv;
            tmax = fmaxf(tmax, sv);
          }
      }
      tmax = fmaxf(tmax, __shfl_xor(tmax, 16));
      tmax = fmaxf(tmax, __shfl_xor(tmax, 32));
      float m_new = fmaxf(m_run, tmax);
      float alpha = __builtin_amdgcn_exp2f(m_run - m_new);
      float rsum = 0.f;
#pragma unroll
      for (int mf = 0; mf < 4; ++mf) {
        short4 pk;
#pragma unroll
        for (int r = 0; r < 4; ++r) {
          float p = __builtin_amdgcn_exp2f(sf[mf][r] - m_new);
          rsum += p;
          ((short*)&pk)[r] = (short)f2bf(p);
        }
        int cbP = 2 * mf + (g >> 1);
        *(short4*)&Ps[wave][q * 64 + 8 * (cbP ^ qx7) + 4 * (g & 1)] = pk;
      }
      rsum += __shfl_xor(rsum, 16);
      rsum += __shfl_xor(rsum, 32);
      l_run = l_run * alpha + rsum;
      m_run = m_new;
#pragma unroll
      for (int mv = 0; mv < 4; ++mv) o[mv] *= alpha;
      // O^T[dv][q] += V^T[dv][kv] * P^T[kv][q]
#pragma unroll
      for (int s = 0; s < 2; ++s) {
        bf16x8 pb = *(const bf16x8*)&Ps[wave][q * 64 + 8 * ((4 * s + g) ^ qx7)];
#pragma unroll
        for (int mv = 0; mv < 4; ++mv) {
          bf16x8 va = *(const bf16x8*)&Vs[(mv * 16 + q) * 64 + 8 * ((4 * s + g) ^ qx7)];
          o[mv] = __builtin_amdgcn_mfma_f32_16x16x32_bf16(va, pb, o[mv], 0, 0, 0);
        }
      }
    }
    float inv = 1.0f / l_run;
    unsigned short* Orow = Ob + ((size_t)(b * SEQ + qg)) * EMB + h * 64;
#pragma unroll
    for (int mv = 0; mv < 4; ++mv) {
      short4 v;
      v.x = (short)f2bf(o[mv][0] * inv);
      v.y = (short)f2bf(o[mv][1] * inv);
      v.z = (short)f2bf(o[mv][2] * inv);
      v.w = (short)f2bf(o[mv][3] * inv);
      *(short4*)&Orow[mv * 16 + 4 * g] = v;
    }
  }
}

extern "C" void kernel_launch(void* const* d_in, const int* in_sizes, int n_in,
                              void* d_out, int out_size, void* d_ws, size_t ws_size,
                              hipStream_t stream) {
  const float* query = (const float*)d_in[0];
  const float* key   = (const float*)d_in[1];
  const float* value = (const float*)d_in[2];
  const int*   pad   = (const int*)d_in[3];
  const float* Wq = (const float*)d_in[4];
  const float* Wk = (const float*)d_in[5];
  const float* Wv = (const float*)d_in[6];
  const float* Wo = (const float*)d_in[7];

  unsigned short* WqT = (unsigned short*)d_ws;
  unsigned short* WkT = WqT + (size_t)EMB * EMB;
  unsigned short* WvT = WkT + (size_t)EMB * EMB;
  unsigned short* WoT = WvT + (size_t)EMB * EMB;
  unsigned short* Qb  = WoT + (size_t)EMB * EMB;
  unsigned short* Kb  = Qb + (size_t)MROWS * EMB;
  unsigned short* VTb = Kb + (size_t)MROWS * EMB;
  unsigned short* Ab  = VTb + (size_t)MROWS * EMB;

  wtrans_kernel<<<dim3(EMB / 32, EMB / 32, 4), dim3(32, 8), 0, stream>>>(
      Wq, Wk, Wv, Wo, WqT, WkT, WvT, WoT);
  gemm_kernel<1, 0><<<dim3(8, 64), 256, 0, stream>>>(query, WqT, Qb);
  gemm_kernel<1, 0><<<dim3(8, 64), 256, 0, stream>>>(key, WkT, Kb);
  gemm_kernel<1, 1><<<dim3(8, 64), 256, 0, stream>>>(value, WvT, VTb);
  attn_kernel<<<dim3(16, NH, BATCH), 256, 0, stream>>>(Qb, Kb, VTb, pad, Ab);
  gemm_kernel<0, 2><<<dim3(8, 64), 256, 0, stream>>>(Ab, WoT, d_out);
}

// Round 3
// 208.388 us; speedup vs baseline: 2.9421x; 1.2674x over previous
//
#include <hip/hip_runtime.h>
#include <hip/hip_bf16.h>

typedef short bf16x8 __attribute__((ext_vector_type(8)));
typedef float f32x4 __attribute__((ext_vector_type(4)));

#define EMB 1024
#define NH 16
#define SEQ 2048
#define BATCH 4
#define MROWS (BATCH * SEQ)

static __device__ inline unsigned short f2bf(float f) {
  unsigned u = __float_as_uint(f);
  u += 0x7fffu + ((u >> 16) & 1u);
  return (unsigned short)(u >> 16);
}

static __device__ inline unsigned cvtpk(float lo, float hi) {
  unsigned r;
  asm("v_cvt_pk_bf16_f32 %0, %1, %2" : "=v"(r) : "v"(lo), "v"(hi));
  return r;
}

static __device__ inline void gload16(const void* g, void* l) {
  __builtin_amdgcn_global_load_lds(
      (const __attribute__((address_space(1))) unsigned int*)g,
      (__attribute__((address_space(3))) unsigned int*)l, 16, 0, 0);
}

// ---------------- weight transpose + cast: W[k][n] f32 -> WT[n][k] bf16 ----------------
// z==0 (Wq) additionally folds in 0.125*log2(e) so attention logits are in exp2 domain.
__global__ __launch_bounds__(256) void wtrans_kernel(
    const float* w0, const float* w1, const float* w2, const float* w3,
    unsigned short* o0, unsigned short* o1, unsigned short* o2, unsigned short* o3) {
  __shared__ float t[32][33];
  int z = blockIdx.z;
  const float* W = z == 0 ? w0 : z == 1 ? w1 : z == 2 ? w2 : w3;
  unsigned short* O = z == 0 ? o0 : z == 1 ? o1 : z == 2 ? o2 : o3;
  float sc = (z == 0) ? 0.18033688011112042f : 1.0f;
  int bx = blockIdx.x * 32;  // k block
  int by = blockIdx.y * 32;  // n block
  int tx = threadIdx.x, ty = threadIdx.y;  // (32,8)
#pragma unroll
  for (int j = 0; j < 4; ++j)
    t[ty + j * 8][tx] = W[(size_t)(bx + ty + j * 8) * EMB + by + tx];
  __syncthreads();
#pragma unroll
  for (int j = 0; j < 4; ++j)
    O[(size_t)(by + ty + j * 8) * EMB + bx + tx] = f2bf(t[tx][ty + j * 8] * sc);
}

// ---------------- GEMM: C[M=8192][N=1024] = A[M][K=1024] * BT[N][K]^T ----------------
// IN_F32: 1 = A is f32 (cast to bf16 while staging), 0 = A is bf16 (global_load_lds)
// OUT_MODE: 0 = bf16 normal [m][n], 1 = bf16 V-transposed [b][h][dv][l], 2 = f32 [m][n]
template <int IN_F32, int OUT_MODE>
__global__ __launch_bounds__(256) void gemm_kernel(const void* Ap, const unsigned short* Bt, void* Cp) {
  __shared__ __align__(16) unsigned short As[128 * 64];  // XOR-swizzled cols
  __shared__ __align__(16) unsigned short Bs[128 * 64];
  const int K = EMB;
  int tid = threadIdx.x;
  int lane = tid & 63, wave = tid >> 6;
  int q = lane & 15, g = lane >> 4;
  int qx7 = q & 7;
  int wm = (wave >> 1) * 64, wn = (wave & 1) * 64;
  // XCD-chunked swizzle: 512 blocks, 64 per XCD -> one XCD owns 8 m-panels x all n
  int lin = blockIdx.x + (blockIdx.y << 3);
  int idx = (lin & 7) * 64 + (lin >> 3);
  int tm = (idx >> 3) * 128, tn = (idx & 7) * 128;
  f32x4 acc[4][4] = {};
  for (int kt = 0; kt < K; kt += 64) {
    if (IN_F32) {
      const float* A = (const float*)Ap;
#pragma unroll
      for (int it = 0; it < 4; ++it) {
        int gid = tid + it * 256;
        int row = gid >> 3, cb = gid & 7;
        const float4* s0 = (const float4*)(A + (size_t)(tm + row) * K + kt + cb * 8);
        float4 x = s0[0], y = s0[1];
        uint4 w;
        w.x = cvtpk(x.x, x.y); w.y = cvtpk(x.z, x.w);
        w.z = cvtpk(y.x, y.y); w.w = cvtpk(y.z, y.w);
        *(uint4*)&As[row * 64 + 8 * (cb ^ (row & 7))] = w;
      }
    } else {
      const unsigned short* A = (const unsigned short*)Ap;
#pragma unroll
      for (int it = 0; it < 4; ++it) {
        int gid = tid + it * 256;
        int row = gid >> 3, cb = gid & 7;
        gload16(A + (size_t)(tm + row) * K + kt + 8 * (cb ^ (row & 7)), &As[gid * 8]);
      }
    }
#pragma unroll
    for (int it = 0; it < 4; ++it) {
      int gid = tid + it * 256;
      int row = gid >> 3, cb = gid & 7;
      gload16(Bt + (size_t)(tn + row) * K + kt + 8 * (cb ^ (row & 7)), &Bs[gid * 8]);
    }
    __syncthreads();
#pragma unroll
    for (int s = 0; s < 2; ++s) {
      bf16x8 af[4], bfr[4];
#pragma unroll
      for (int mf = 0; mf < 4; ++mf)
        af[mf] = *(const bf16x8*)&As[(wm + mf * 16 + q) * 64 + 8 * ((4 * s + g) ^ qx7)];
#pragma unroll
      for (int nf = 0; nf < 4; ++nf)
        bfr[nf] = *(const bf16x8*)&Bs[(wn + nf * 16 + q) * 64 + 8 * ((4 * s + g) ^ qx7)];
#pragma unroll
      for (int mf = 0; mf < 4; ++mf)
#pragma unroll
        for (int nf = 0; nf < 4; ++nf)
          acc[mf][nf] = __builtin_amdgcn_mfma_f32_16x16x32_bf16(af[mf], bfr[nf], acc[mf][nf], 0, 0, 0);
    }
    __syncthreads();
  }
  if (OUT_MODE == 0) {
    unsigned short* C = (unsigned short*)Cp;
#pragma unroll
    for (int mf = 0; mf < 4; ++mf)
#pragma unroll
      for (int nf = 0; nf < 4; ++nf)
#pragma unroll
        for (int r = 0; r < 4; ++r) {
          int row = tm + wm + mf * 16 + 4 * g + r;
          int col = tn + wn + nf * 16 + q;
          C[(size_t)row * EMB + col] = f2bf(acc[mf][nf][r]);
        }
  } else if (OUT_MODE == 1) {
    unsigned short* C = (unsigned short*)Cp;
#pragma unroll
    for (int mf = 0; mf < 4; ++mf) {
      int m0 = tm + wm + mf * 16 + 4 * g;
      int b = m0 >> 11, l = m0 & 2047;
#pragma unroll
      for (int nf = 0; nf < 4; ++nf) {
        int n = tn + wn + nf * 16 + q;
        int h = n >> 6, dv = n & 63;
        uint2 w;
        w.x = cvtpk(acc[mf][nf][0], acc[mf][nf][1]);
        w.y = cvtpk(acc[mf][nf][2], acc[mf][nf][3]);
        *(uint2*)&C[(((size_t)b * NH + h) * 64 + dv) * SEQ + l] = w;
      }
    }
  } else {
    float* C = (float*)Cp;
#pragma unroll
    for (int mf = 0; mf < 4; ++mf)
#pragma unroll
      for (int nf = 0; nf < 4; ++nf)
#pragma unroll
        for (int r = 0; r < 4; ++r) {
          int row = tm + wm + mf * 16 + 4 * g + r;
          int col = tn + wn + nf * 16 + q;
          C[(size_t)row * EMB + col] = acc[mf][nf][r];
        }
  }
}

// ---------------- flash attention: dbuf global_load_lds staging, swapped operands ----------------
// Q,K bf16 [b][l][h*64+d] (Q pre-scaled by 0.125*log2e); VT bf16 [b][h][dv][l]; out bf16.
__global__ __launch_bounds__(256) void attn_kernel(
    const unsigned short* Qb, const unsigned short* Kb, const unsigned short* VTb,
    const int* pad, unsigned short* Ob) {
  __shared__ __align__(16) unsigned short Ks[2][64 * 64];   // [kv][d], src-XOR-swizzled
  __shared__ __align__(16) unsigned short Vs[2][64 * 64];   // [dv][kv], src-XOR-swizzled
  __shared__ __align__(16) unsigned short Ps[4][16 * 64];   // per-wave P, XOR-swizzled
  int tid = threadIdx.x;
  int lane = tid & 63, wave = tid >> 6;
  int q = lane & 15, g = lane >> 4;
  int qx7 = q & 7;
  // XCD-chunked swizzle: 1024 blocks, 128/XCD -> 8 (b,h) pairs per XCD share K/V in L2
  int lin = blockIdx.x;
  int idx = (lin & 7) * 128 + (lin >> 3);
  int b = idx >> 8, h = (idx >> 4) & 15, px = idx & 15;

  int srow = tid >> 3, scb = tid & 7;
  int ssw = 8 * (scb ^ (srow & 7));  // swizzled col (elements); row&7 invariant under +32
  const unsigned short* Kbase = Kb + (size_t)b * SEQ * EMB + (size_t)srow * EMB + h * 64 + ssw;
  const unsigned short* Vbase = VTb + (((size_t)(b * NH + h)) * 64 + srow) * SEQ + ssw;

#pragma unroll 1
  for (int half = 0; half < 2; ++half) {
    int c = half ? 31 - px : px;
    int qg = c * 64 + wave * 16 + q;
    const unsigned short* Qrow = Qb + ((size_t)(b * SEQ + qg)) * EMB + h * 64;
    bf16x8 qf0 = *(const bf16x8*)(Qrow + 8 * g);
    bf16x8 qf1 = *(const bf16x8*)(Qrow + 32 + 8 * g);
    f32x4 o[4] = {};
    float m_run = -INFINITY, l_run = 0.f;

    // prologue: stage tile 0 into buf 0
#pragma unroll
    for (int it = 0; it < 2; ++it) {
      gload16(Kbase + (size_t)(it * 32) * EMB, &Ks[0][(tid + it * 256) * 8]);
      gload16(Vbase + it * 32 * SEQ, &Vs[0][(tid + it * 256) * 8]);
    }
    __syncthreads();

#pragma unroll 1
    for (int t = 0; t <= c; ++t) {
      int kvt = t * 64;
      int cur = t & 1;
      if (t < c) {  // issue next-tile loads; they complete by the loop-end barrier
#pragma unroll
        for (int it = 0; it < 2; ++it) {
          gload16(Kbase + (size_t)(kvt + 64 + it * 32) * EMB, &Ks[cur ^ 1][(tid + it * 256) * 8]);
          gload16(Vbase + (size_t)(kvt + 64) + it * 32 * SEQ, &Vs[cur ^ 1][(tid + it * 256) * 8]);
        }
      }
      int pv = pad[b * SEQ + kvt + lane];
      unsigned long long pmask = __ballot(pv != 0);
      // S^T[kv 64][q 16] = K * Q^T  (already in log2 domain via pre-scaled Q)
      f32x4 sf[4] = {};
      __builtin_amdgcn_s_setprio(1);
#pragma unroll
      for (int s = 0; s < 2; ++s) {
#pragma unroll
        for (int mf = 0; mf < 4; ++mf) {
          bf16x8 kf = *(const bf16x8*)&Ks[cur][(mf * 16 + q) * 64 + 8 * ((4 * s + g) ^ qx7)];
          sf[mf] = __builtin_amdgcn_mfma_f32_16x16x32_bf16(kf, s ? qf1 : qf0, sf[mf], 0, 0, 0);
        }
      }
      __builtin_amdgcn_s_setprio(0);
      float tmax = -INFINITY;
      bool full = (t < c) && (pmask == ~0ull);
      if (full) {
#pragma unroll
        for (int mf = 0; mf < 4; ++mf)
#pragma unroll
          for (int r = 0; r < 4; ++r) tmax = fmaxf(tmax, sf[mf][r]);
      } else {
#pragma unroll
        for (int mf = 0; mf < 4; ++mf)
#pragma unroll
          for (int r = 0; r < 4; ++r) {
            int kvl = mf * 16 + 4 * g + r;
            bool keep = (kvt + kvl <= qg) && ((pmask >> kvl) & 1ULL);
            float sv = keep ? sf[mf][r] : -INFINITY;
            sf[mf][r] = sv;
            tmax = fmaxf(tmax, sv);
          }
      }
      tmax = fmaxf(tmax, __shfl_xor(tmax, 16));
      tmax = fmaxf(tmax, __shfl_xor(tmax, 32));
      // defer-max (log2 domain, THR=8): skip O-rescale when max barely grows
      if (!__all(tmax <= m_run + 8.0f)) {
        float m_new = fmaxf(m_run, tmax);
        float alpha = __builtin_amdgcn_exp2f(m_run - m_new);
        l_run *= alpha;
#pragma unroll
        for (int mv = 0; mv < 4; ++mv) o[mv] *= alpha;
        m_run = m_new;
      }
      float rsum = 0.f;
      float pvv[16];
#pragma unroll
      for (int mf = 0; mf < 4; ++mf)
#pragma unroll
        for (int r = 0; r < 4; ++r) {
          float p = __builtin_amdgcn_exp2f(sf[mf][r] - m_run);
          pvv[mf * 4 + r] = p;
          rsum += p;
        }
#pragma unroll
      for (int mf = 0; mf < 4; ++mf) {
        uint2 w;
        w.x = cvtpk(pvv[mf * 4 + 0], pvv[mf * 4 + 1]);
        w.y = cvtpk(pvv[mf * 4 + 2], pvv[mf * 4 + 3]);
        int cbP = 2 * mf + (g >> 1);
        *(uint2*)&Ps[wave][q * 64 + 8 * (cbP ^ qx7) + 4 * (g & 1)] = w;
      }
      rsum += __shfl_xor(rsum, 16);
      rsum += __shfl_xor(rsum, 32);
      l_run += rsum;
      // O^T[dv][q] += V^T[dv][kv] * P^T[kv][q]
      __builtin_amdgcn_s_setprio(1);
#pragma unroll
      for (int s = 0; s < 2; ++s) {
        bf16x8 pb = *(const bf16x8*)&Ps[wave][q * 64 + 8 * ((4 * s + g) ^ qx7)];
#pragma unroll
        for (int mv = 0; mv < 4; ++mv) {
          bf16x8 va = *(const bf16x8*)&Vs[cur][(mv * 16 + q) * 64 + 8 * ((4 * s + g) ^ qx7)];
          o[mv] = __builtin_amdgcn_mfma_f32_16x16x32_bf16(va, pb, o[mv], 0, 0, 0);
        }
      }
      __builtin_amdgcn_s_setprio(0);
      __syncthreads();  // publishes buf cur^1, protects buf cur for overwrite at t+2
    }
    float inv = 1.0f / l_run;
    unsigned short* Orow = Ob + ((size_t)(b * SEQ + qg)) * EMB + h * 64;
#pragma unroll
    for (int mv = 0; mv < 4; ++mv) {
      uint2 w;
      w.x = cvtpk(o[mv][0] * inv, o[mv][1] * inv);
      w.y = cvtpk(o[mv][2] * inv, o[mv][3] * inv);
      *(uint2*)&Orow[mv * 16 + 4 * g] = w;
    }
  }
}

extern "C" void kernel_launch(void* const* d_in, const int* in_sizes, int n_in,
                              void* d_out, int out_size, void* d_ws, size_t ws_size,
                              hipStream_t stream) {
  const float* query = (const float*)d_in[0];
  const float* key   = (const float*)d_in[1];
  const float* value = (const float*)d_in[2];
  const int*   pad   = (const int*)d_in[3];
  const float* Wq = (const float*)d_in[4];
  const float* Wk = (const float*)d_in[5];
  const float* Wv = (const float*)d_in[6];
  const float* Wo = (const float*)d_in[7];

  unsigned short* WqT = (unsigned short*)d_ws;
  unsigned short* WkT = WqT + (size_t)EMB * EMB;
  unsigned short* WvT = WkT + (size_t)EMB * EMB;
  unsigned short* WoT = WvT + (size_t)EMB * EMB;
  unsigned short* Qb  = WoT + (size_t)EMB * EMB;
  unsigned short* Kb  = Qb + (size_t)MROWS * EMB;
  unsigned short* VTb = Kb + (size_t)MROWS * EMB;
  unsigned short* Ab  = VTb + (size_t)MROWS * EMB;

  wtrans_kernel<<<dim3(EMB / 32, EMB / 32, 4), dim3(32, 8), 0, stream>>>(
      Wq, Wk, Wv, Wo, WqT, WkT, WvT, WoT);
  gemm_kernel<1, 0><<<dim3(8, 64), 256, 0, stream>>>(query, WqT, Qb);
  gemm_kernel<1, 0><<<dim3(8, 64), 256, 0, stream>>>(key, WkT, Kb);
  gemm_kernel<1, 1><<<dim3(8, 64), 256, 0, stream>>>(value, WvT, VTb);
  attn_kernel<<<dim3(1024), 256, 0, stream>>>(Qb, Kb, VTb, pad, Ab);
  gemm_kernel<0, 2><<<dim3(8, 64), 256, 0, stream>>>(Ab, WoT, d_out);
}